// Round 9
// baseline (2585.271 us; speedup 1.0000x reference)
//
#include <hip/hip_runtime.h>
#include <hip/hip_bf16.h>
#include <math.h>

#define NTOT 262144

typedef unsigned short u16;
typedef unsigned int u32;

__device__ __forceinline__ float bf2f(u32 lo16) { return __uint_as_float(lo16 << 16); }
__device__ __forceinline__ u16 f2bf(float f) {  // round-to-nearest-even
  u32 x = __float_as_uint(f);
  return (u16)((x + 0x7FFFu + ((x >> 16) & 1u)) >> 16);
}

// ---------------------------------------------------------------------------
// Hilbert encode (Skilling AxesToTranspose + interleave), order 10, branchless
// ---------------------------------------------------------------------------
__device__ __forceinline__ unsigned int hilbert10(unsigned int X0, unsigned int X1, unsigned int X2) {
#pragma unroll
  for (unsigned int Q = 512u; Q > 1u; Q >>= 1) {
    unsigned int P = Q - 1u;
    X0 ^= (X0 & Q) ? P : 0u;
    {
      unsigned int t = (X0 ^ X1) & P;
      bool c = (X1 & Q) != 0u;
      X0 ^= c ? P : t;
      X1 ^= c ? 0u : t;
    }
    {
      unsigned int t = (X0 ^ X2) & P;
      bool c = (X2 & Q) != 0u;
      X0 ^= c ? P : t;
      X2 ^= c ? 0u : t;
    }
  }
  X1 ^= X0;
  X2 ^= X1;
  unsigned int t = 0u;
#pragma unroll
  for (unsigned int Q = 512u; Q > 1u; Q >>= 1) t ^= (X2 & Q) ? (Q - 1u) : 0u;
  X0 ^= t; X1 ^= t; X2 ^= t;
  unsigned int code = 0u;
#pragma unroll
  for (int b = 9; b >= 0; b--) {
    code = (code << 3) | (((X0 >> b) & 1u) << 2) | (((X1 >> b) & 1u) << 1) | ((X2 >> b) & 1u);
  }
  return code;
}

// Reference runs under JAX default x64-DISABLED: batched_codes is int32 and
// (batch << 30) WRAPS for batch>=2, so signed-ascending argsort orders batches
// [2,3,0,1]. Unsigned-monotone equivalent: batch -> batch^2 in the high bits.
__global__ __launch_bounds__(256) void k_codes(const int* __restrict__ coors,
                                               unsigned long long* __restrict__ keys) {
  int r = blockIdx.x * 256 + threadIdx.x;
  int4 cc = ((const int4*)coors)[r];  // (b, x, y, z)
  unsigned long long b = (unsigned long long)((unsigned int)cc.x ^ 2u);
  unsigned int c1 = hilbert10((unsigned)cc.y, (unsigned)cc.z, (unsigned)cc.w);
  unsigned int c2 = hilbert10((unsigned)cc.y, (unsigned)(cc.z + 1), (unsigned)(cc.w + 1));
  unsigned long long bc1 = (b << 30) | (unsigned long long)c1;
  unsigned long long bc2 = (b << 30) | (unsigned long long)c2;
  keys[r] = (bc1 << 18) | (unsigned long long)(unsigned)r;
  keys[NTOT + r] = (bc2 << 18) | (unsigned long long)(unsigned)r;
}

// ---------------------------------------------------------------------------
// Bitonic sort, N = 2^18, two independent arrays selected by blockIdx.y
// ---------------------------------------------------------------------------
__global__ __launch_bounds__(256) void k_bitonic_local(unsigned long long* __restrict__ keys) {
  unsigned long long* a = keys + (size_t)blockIdx.y * NTOT;
  int base = blockIdx.x * 2048;
  __shared__ unsigned long long s[2048];
  for (int i = threadIdx.x; i < 2048; i += 256) s[i] = a[base + i];
  __syncthreads();
  for (int k = 2; k <= 2048; k <<= 1) {
    for (int j = k >> 1; j > 0; j >>= 1) {
      for (int p = threadIdx.x; p < 1024; p += 256) {
        int i = ((p & ~(j - 1)) << 1) | (p & (j - 1));
        int ix = i | j;
        bool asc = (((base + i) & k) == 0);
        unsigned long long x = s[i], y = s[ix];
        if ((x > y) == asc) { s[i] = y; s[ix] = x; }
      }
      __syncthreads();
    }
  }
  for (int i = threadIdx.x; i < 2048; i += 256) a[base + i] = s[i];
}

__global__ __launch_bounds__(256) void k_bitonic_global(unsigned long long* __restrict__ keys,
                                                        int k, int j) {
  unsigned long long* a = keys + (size_t)blockIdx.y * NTOT;
  int p = blockIdx.x * 256 + threadIdx.x;          // p < N/2
  int i = ((p & ~(j - 1)) << 1) | (p & (j - 1));
  int ix = i | j;
  bool asc = ((i & k) == 0);
  unsigned long long x = a[i], y = a[ix];
  if ((x > y) == asc) { a[i] = y; a[ix] = x; }
}

__global__ __launch_bounds__(256) void k_bitonic_finish(unsigned long long* __restrict__ keys,
                                                        int k) {
  unsigned long long* a = keys + (size_t)blockIdx.y * NTOT;
  int base = blockIdx.x * 2048;
  __shared__ unsigned long long s[2048];
  for (int i = threadIdx.x; i < 2048; i += 256) s[i] = a[base + i];
  __syncthreads();
  bool asc = ((base & k) == 0);
  for (int j = 1024; j > 0; j >>= 1) {
    for (int p = threadIdx.x; p < 1024; p += 256) {
      int i = ((p & ~(j - 1)) << 1) | (p & (j - 1));
      int ix = i | j;
      unsigned long long x = s[i], y = s[ix];
      if ((x > y) == asc) { s[i] = y; s[ix] = x; }
    }
    __syncthreads();
  }
  for (int i = threadIdx.x; i < 2048; i += 256) a[base + i] = s[i];
}

__global__ __launch_bounds__(256) void k_extract(const unsigned long long* __restrict__ keys,
                                                 int* __restrict__ ind1, int* __restrict__ ind2,
                                                 int* __restrict__ inv1) {
  int r = blockIdx.x * 256 + threadIdx.x;
  int e1 = (int)(keys[r] & 0x3FFFFULL);
  int e2 = (int)(keys[NTOT + r] & 0x3FFFFULL);
  ind1[r] = e1;
  ind2[r] = e2;
  inv1[e1] = r;
}

__global__ __launch_bounds__(256) void k_compose(const int* __restrict__ ind2,
                                                 const int* __restrict__ inv1,
                                                 int* __restrict__ ind12) {
  int r = blockIdx.x * 256 + threadIdx.x;
  ind12[r] = inv1[ind2[r]];
}

// ---------------------------------------------------------------------------
__device__ __forceinline__ float gelu_tanh(float v) {
  float u = 0.7978845608028654f * (v + 0.044715f * v * v * v);
  float e = __expf(2.f * u);
  float t = 1.f - 2.f / (e + 1.f);
  return 0.5f * v * (1.f + t);
}

// ---------------------------------------------------------------------------
// Fully fused VoxFormer block: gather + pos + LN + qkv + attention + o@w_o
// + residual + FFN. One workgroup (4 waves) per group of 64 rows.
// Static LDS = 64 KB. Weights/pts f32. src: f32 (srcF) or bf16 (srcB).
// Output: bf16 (outB) or f32 (outF).
// ---------------------------------------------------------------------------
__global__ __launch_bounds__(256) void k_block(
    const float* __restrict__ srcF, const u16* __restrict__ srcB,
    const float* __restrict__ pts,
    const int* __restrict__ indF, const int* __restrict__ indP,
    const float* __restrict__ w_pos, const float* __restrict__ w_qkv,
    const float* __restrict__ w_o, const float* __restrict__ w_ffa,
    const float* __restrict__ w_ffb,
    u16* __restrict__ outB, float* __restrict__ outF) {
  __shared__ float qkv_s[64 * 192];  // 48 KB
  __shared__ float wch[64 * 64];     // 16 KB
  const int tid = threadIdx.x;
  const int lane = tid & 63;
  const int w = tid >> 6;
  const int base = blockIdx.x * 64;

  // --- phase 0: gather + pos-inject + LayerNorm (x, ln in registers)
  float wp0 = w_pos[lane], wp1 = w_pos[64 + lane], wp2 = w_pos[128 + lane], wp3 = w_pos[192 + lane];
  float xr[16], lnr[16];
#pragma unroll
  for (int rr = 0; rr < 16; rr++) {
    int r = base + w * 16 + rr;
    int iF = indF[r];
    int iP = indP[r];
    float x = srcB ? bf2f(srcB[(size_t)iF * 64 + lane]) : srcF[(size_t)iF * 64 + lane];
    float4 pc = ((const float4*)pts)[iP];
    x += pc.x * wp0 + pc.y * wp1 + pc.z * wp2 + pc.w * wp3;
    xr[rr] = x;
    float s = x, s2 = x * x;
#pragma unroll
    for (int o = 32; o > 0; o >>= 1) { s += __shfl_xor(s, o, 64); s2 += __shfl_xor(s2, o, 64); }
    float mean = s * 0.015625f;
    float var = s2 * 0.015625f - mean * mean;
    lnr[rr] = (x - mean) * rsqrtf(var + 1e-5f);
  }

  // --- phase 1: qkv GEMM, 3 chunks (q, k, v); ln broadcast via __shfl
  for (int c = 0; c < 3; c++) {
    __syncthreads();
    for (int e = tid * 4; e < 4096; e += 1024) {
      int k = e >> 6, j = e & 63;
      *(float4*)&wch[e] = *(const float4*)&w_qkv[(size_t)k * 192 + c * 64 + j];
    }
    __syncthreads();
    float acc[16];
#pragma unroll
    for (int rr = 0; rr < 16; rr++) acc[rr] = 0.f;
#pragma unroll 2
    for (int k = 0; k < 64; k++) {
      float wv = wch[k * 64 + lane];
#pragma unroll
      for (int rr = 0; rr < 16; rr++) acc[rr] += __shfl(lnr[rr], k, 64) * wv;
    }
#pragma unroll
    for (int rr = 0; rr < 16; rr++)
      qkv_s[(w * 16 + rr) * 192 + c * 64 + lane] = acc[rr];
  }
  __syncthreads();

  // --- phase 2: attention (wave = head, lane = query row, online softmax)
  const int h = w;
  const float4* qp = (const float4*)(qkv_s + lane * 192 + 16 * h);
  float4 q0 = qp[0], q1 = qp[1], q2 = qp[2], q3 = qp[3];
  float m = -INFINITY, l = 0.f;
  float4 a0 = {0, 0, 0, 0}, a1 = {0, 0, 0, 0}, a2 = {0, 0, 0, 0}, a3 = {0, 0, 0, 0};
  for (int j = 0; j < 64; j++) {
    const float4* kp = (const float4*)(qkv_s + j * 192 + 64 + 16 * h);
    float4 k0 = kp[0], k1 = kp[1], k2 = kp[2], k3 = kp[3];
    float s = q0.x * k0.x + q0.y * k0.y + q0.z * k0.z + q0.w * k0.w
            + q1.x * k1.x + q1.y * k1.y + q1.z * k1.z + q1.w * k1.w
            + q2.x * k2.x + q2.y * k2.y + q2.z * k2.z + q2.w * k2.w
            + q3.x * k3.x + q3.y * k3.y + q3.z * k3.z + q3.w * k3.w;
    s *= 0.25f;
    float mn = fmaxf(m, s);
    float corr = __expf(m - mn);
    float p = __expf(s - mn);
    l = l * corr + p;
    const float4* vp = (const float4*)(qkv_s + j * 192 + 128 + 16 * h);
    float4 v0 = vp[0], v1 = vp[1], v2 = vp[2], v3 = vp[3];
    a0.x = a0.x * corr + p * v0.x; a0.y = a0.y * corr + p * v0.y;
    a0.z = a0.z * corr + p * v0.z; a0.w = a0.w * corr + p * v0.w;
    a1.x = a1.x * corr + p * v1.x; a1.y = a1.y * corr + p * v1.y;
    a1.z = a1.z * corr + p * v1.z; a1.w = a1.w * corr + p * v1.w;
    a2.x = a2.x * corr + p * v2.x; a2.y = a2.y * corr + p * v2.y;
    a2.z = a2.z * corr + p * v2.z; a2.w = a2.w * corr + p * v2.w;
    a3.x = a3.x * corr + p * v3.x; a3.y = a3.y * corr + p * v3.y;
    a3.z = a3.z * corr + p * v3.z; a3.w = a3.w * corr + p * v3.w;
    m = mn;
  }
  float inv = 1.f / l;
  __syncthreads();  // all waves done reading q/k/v before LDS reuse

  float* o_s = qkv_s;   // [64][68] tile, 4352 floats (inside qkv_s)
  float* wo_s = wch;    // 4096 floats
  {
    float4 ov;
    ov = make_float4(a0.x * inv, a0.y * inv, a0.z * inv, a0.w * inv);
    *(float4*)&o_s[lane * 68 + 16 * h + 0] = ov;
    ov = make_float4(a1.x * inv, a1.y * inv, a1.z * inv, a1.w * inv);
    *(float4*)&o_s[lane * 68 + 16 * h + 4] = ov;
    ov = make_float4(a2.x * inv, a2.y * inv, a2.z * inv, a2.w * inv);
    *(float4*)&o_s[lane * 68 + 16 * h + 8] = ov;
    ov = make_float4(a3.x * inv, a3.y * inv, a3.z * inv, a3.w * inv);
    *(float4*)&o_s[lane * 68 + 16 * h + 12] = ov;
  }
  for (int e = tid * 4; e < 4096; e += 1024)
    *(float4*)&wo_s[e] = *(const float4*)&w_o[e];
  __syncthreads();

  // --- phase 3: x2 = x + o @ w_o (kept in registers)
  float x2r[16];
#pragma unroll
  for (int qq = 0; qq < 16; qq++) {
    int r = w * 16 + qq;
    float a = xr[qq];
    const float* orow = o_s + r * 68;
#pragma unroll 4
    for (int k0i = 0; k0i < 64; k0i += 4) {
      float4 o4 = *(const float4*)(orow + k0i);
      a += o4.x * wo_s[(k0i + 0) * 64 + lane];
      a += o4.y * wo_s[(k0i + 1) * 64 + lane];
      a += o4.z * wo_s[(k0i + 2) * 64 + lane];
      a += o4.w * wo_s[(k0i + 3) * 64 + lane];
    }
    x2r[qq] = a;
  }
  __syncthreads();  // o_s / wo_s reads done before FFN repurposes LDS

  // --- phase 4: FFN  out = x2 + gelu(LN(x2) @ w_ffa) @ w_ffb
  // LDS repurpose: wa = qkv_s[0,4096), wb = qkv_s[4096,8192),
  //                hT = qkv_s[8192,12288), lnT = wch (per-wave [64][16] tiles)
  float* wa = qkv_s;
  float* wb = qkv_s + 4096;
  float* hw = qkv_s + 8192 + w * 1024;  // [col][row] per-wave
  float* lnw = wch + w * 1024;          // [col][row] per-wave
  float acc2[16];
#pragma unroll
  for (int rr = 0; rr < 16; rr++) {
    float x = x2r[rr];
    acc2[rr] = x;
    float s = x, s2 = x * x;
#pragma unroll
    for (int o = 32; o > 0; o >>= 1) { s += __shfl_xor(s, o, 64); s2 += __shfl_xor(s2, o, 64); }
    float mean = s * 0.015625f;
    float var = s2 * 0.015625f - mean * mean;
    lnw[lane * 16 + rr] = (x - mean) * rsqrtf(var + 1e-5f);
  }
  for (int c = 0; c < 4; c++) {
    __syncthreads();  // prior chunk's wa/wb fully consumed
    for (int e = tid * 4; e < 4096; e += 1024) {
      int k = e >> 6, j = e & 63;
      *(float4*)&wa[e] = *(const float4*)&w_ffa[(size_t)k * 256 + c * 64 + j];
      *(float4*)&wb[e] = *(const float4*)&w_ffb[(size_t)c * 4096 + e];
    }
    __syncthreads();
    float hreg[16];
#pragma unroll
    for (int rr = 0; rr < 16; rr++) hreg[rr] = 0.f;
#pragma unroll 2
    for (int k = 0; k < 64; k++) {
      float wv = wa[k * 64 + lane];
      float4 l0 = *(const float4*)(lnw + k * 16);
      float4 l1 = *(const float4*)(lnw + k * 16 + 4);
      float4 l2 = *(const float4*)(lnw + k * 16 + 8);
      float4 l3 = *(const float4*)(lnw + k * 16 + 12);
      float lv[16] = {l0.x, l0.y, l0.z, l0.w, l1.x, l1.y, l1.z, l1.w,
                      l2.x, l2.y, l2.z, l2.w, l3.x, l3.y, l3.z, l3.w};
#pragma unroll
      for (int rr = 0; rr < 16; rr++) hreg[rr] += lv[rr] * wv;
    }
#pragma unroll
    for (int rr = 0; rr < 16; rr++) hw[lane * 16 + rr] = gelu_tanh(hreg[rr]);
    // hw per-wave: same-wave LDS write->read is in-order, no barrier needed
#pragma unroll 2
    for (int k = 0; k < 64; k++) {
      float wv = wb[k * 64 + lane];
      float4 h0 = *(const float4*)(hw + k * 16);
      float4 h1 = *(const float4*)(hw + k * 16 + 4);
      float4 h2 = *(const float4*)(hw + k * 16 + 8);
      float4 h3 = *(const float4*)(hw + k * 16 + 12);
      float hv[16] = {h0.x, h0.y, h0.z, h0.w, h1.x, h1.y, h1.z, h1.w,
                      h2.x, h2.y, h2.z, h2.w, h3.x, h3.y, h3.z, h3.w};
#pragma unroll
      for (int rr = 0; rr < 16; rr++) acc2[rr] += hv[rr] * wv;
    }
  }
#pragma unroll
  for (int rr = 0; rr < 16; rr++) {
    size_t idx = (size_t)(base + w * 16 + rr) * 64 + lane;
    if (outB) outB[idx] = f2bf(acc2[rr]);
    else outF[idx] = acc2[rr];
  }
}

// ---------------------------------------------------------------------------
extern "C" void kernel_launch(void* const* d_in, const int* in_sizes, int n_in,
                              void* d_out, int out_size, void* d_ws, size_t ws_size,
                              hipStream_t stream) {
  const float* vox_feats = (const float*)d_in[0];
  const float* pts = (const float*)d_in[1];
  const int* coors = (const int*)d_in[2];
  const float* w_pos1 = (const float*)d_in[6];
  const float* w_qkv1 = (const float*)d_in[7];
  const float* w_o1 = (const float*)d_in[8];
  const float* w_ffa1 = (const float*)d_in[9];
  const float* w_ffb1 = (const float*)d_in[10];
  const float* w_pos2 = (const float*)d_in[11];
  const float* w_qkv2 = (const float*)d_in[12];
  const float* w_o2 = (const float*)d_in[13];
  const float* w_ffa2 = (const float*)d_in[14];
  const float* w_ffb2 = (const float*)d_in[15];

  // Workspace (40 MiB; ws_size >= 41 MiB proven in R8):
  //   [0, 4 MiB)  ind1 | ind2 | inv1 | ind12
  //   [4, 8 MiB)  keys (2N u64)
  //   [8, 40 MiB) f1 (N x 64 bf16 block-1 output)  -- no aliasing
  char* ws = (char*)d_ws;
  int* ind1 = (int*)ws;
  int* ind2 = ind1 + NTOT;
  int* inv1 = ind2 + NTOT;
  int* ind12 = inv1 + NTOT;
  unsigned long long* keys = (unsigned long long*)(ws + ((size_t)4 << 20));
  u16* f1 = (u16*)(ws + ((size_t)8 << 20));
  float* outp = (float*)d_out;

  // --- mapping: codes + 2x bitonic sort (both key arrays via gridDim.y)
  k_codes<<<NTOT / 256, 256, 0, stream>>>(coors, keys);
  k_bitonic_local<<<dim3(128, 2), 256, 0, stream>>>(keys);
  for (int k = 4096; k <= NTOT; k <<= 1) {
    for (int j = k >> 1; j >= 2048; j >>= 1)
      k_bitonic_global<<<dim3(512, 2), 256, 0, stream>>>(keys, k, j);
    k_bitonic_finish<<<dim3(128, 2), 256, 0, stream>>>(keys, k);
  }
  k_extract<<<NTOT / 256, 256, 0, stream>>>(keys, ind1, ind2, inv1);
  k_compose<<<NTOT / 256, 256, 0, stream>>>(ind2, inv1, ind12);

  // --- block 1 (f32 feats+pts by ind1) -> f1 (bf16, ws)
  k_block<<<NTOT / 64, 256, 0, stream>>>(vox_feats, (const u16*)nullptr, pts,
                                         ind1, ind1, w_pos1, w_qkv1, w_o1,
                                         w_ffa1, w_ffb1, f1, (float*)nullptr);
  // --- block 2 (bf16 f1 by ind12, pts by ind2) -> d_out (f32)
  k_block<<<NTOT / 64, 256, 0, stream>>>((const float*)nullptr, f1, pts,
                                         ind12, ind2, w_pos2, w_qkv2, w_o2,
                                         w_ffa2, w_ffb2, (u16*)nullptr, outp);
}